// Round 10
// baseline (146.940 us; speedup 1.0000x reference)
//
#include <hip/hip_runtime.h>

#define EMB 300
#define EMB4 75            // 300/4
#define NBLK 1024
#define NTHR 256
#define NWAVES (NBLK * NTHR / 64)   // 4096

struct Ctrl { int arrive; int release; };

// One persistent kernel, static work partitioning throughout:
//   phase 0: boundary sweep of sorted segment_ids -> bounds[]
//   phase 1: dot2[v] = (emb[v]·W[:300], emb[v]·W[300:]) — static grid-stride
//   barrier: arrive/release grid barrier (all 1024 blocks resident:
//            launch_bounds(256,4) caps VGPR<=128 -> 4 blocks/CU x 256 CU)
//   phase 2: per-pair gather + mean + sigmoid
__global__ __launch_bounds__(NTHR, 4)
void mega_kernel(const float* __restrict__ emb,
                 const float* __restrict__ W,
                 const int* __restrict__ token_ids,
                 const int* __restrict__ segment_ids,
                 const float* __restrict__ bptr,
                 float2* __restrict__ dot2,
                 int* __restrict__ bounds,
                 Ctrl* __restrict__ ctrl,
                 float* __restrict__ out,
                 int vocab, int T, int nseg, int pairs) {
    const int gtid = blockIdx.x * NTHR + threadIdx.x;
    const int lane = threadIdx.x & 63;
    const int w    = gtid >> 6;

    // ---- phase 0: segment boundaries (sorted ids -> transition scan) ----
    for (int j = gtid; j < T; j += NBLK * NTHR) {
        int cur = segment_ids[j];
        if (j == 0) {
            for (int s = 0; s <= cur; ++s) bounds[s] = 0;
        } else {
            int prev = segment_ids[j - 1];
            for (int s = prev + 1; s <= cur; ++s) bounds[s] = j;
        }
        if (j == T - 1) {
            for (int s = cur + 1; s <= nseg; ++s) bounds[s] = T;
        }
    }

    // ---- phase 1: dot products, 4 rows per wave-iteration, static stride ----
    const float4* W4 = (const float4*)W;   // 600 floats = 150 float4
    const int l  = lane & 15;              // lane within 16-lane group
    const int gq = lane >> 4;              // which of the wave's 4 rows

    float4 wa[5], wb[5];
    #pragma unroll
    for (int it = 0; it < 5; ++it) {
        int k = l + it * 16;
        wa[it] = (k < EMB4) ? W4[k]        : make_float4(0.f, 0.f, 0.f, 0.f);
        wb[it] = (k < EMB4) ? W4[EMB4 + k] : make_float4(0.f, 0.f, 0.f, 0.f);
    }

    const int  ngroups = vocab >> 2;          // vocab = 100000, divisible by 4
    const bool tail_ok = (l < EMB4 - 64);     // l < 11: 5th float4 exists
    for (int rg = w; rg < ngroups; rg += NWAVES) {
        unsigned row = (unsigned)(rg * 4 + gq);
        const float4* e4 = (const float4*)(emb + row * (unsigned)EMB);

        float a = 0.f, b = 0.f;
        #pragma unroll
        for (int it = 0; it < 4; ++it) {      // k = l + 16*it < 64 < 75 always
            float4 v = e4[l + it * 16];
            a += v.x * wa[it].x + v.y * wa[it].y + v.z * wa[it].z + v.w * wa[it].w;
            b += v.x * wb[it].x + v.y * wb[it].y + v.z * wb[it].z + v.w * wb[it].w;
        }
        if (tail_ok) {                        // masked tail, k = l + 64 < 75
            float4 v = e4[l + 64];
            a += v.x * wa[4].x + v.y * wa[4].y + v.z * wa[4].z + v.w * wa[4].w;
            b += v.x * wb[4].x + v.y * wb[4].y + v.z * wb[4].z + v.w * wb[4].w;
        }
        #pragma unroll
        for (int m = 8; m > 0; m >>= 1) {
            a += __shfl_xor(a, m, 64);
            b += __shfl_xor(b, m, 64);
        }
        if (l == 0) dot2[row] = make_float2(a, b);
    }

    // ---- grid barrier (R8 protocol: functionally verified, no work-steal) ----
    __syncthreads();
    if (threadIdx.x == 0) {
        __threadfence();  // publish this block's dot2/bounds writes
        int prev = atomicAdd(&ctrl->arrive, 1);   // device scope
        if (prev == NBLK - 1) {
            __hip_atomic_store(&ctrl->release, 1, __ATOMIC_RELEASE,
                               __HIP_MEMORY_SCOPE_AGENT);
        } else {
            while (__hip_atomic_load(&ctrl->release, __ATOMIC_ACQUIRE,
                                     __HIP_MEMORY_SCOPE_AGENT) == 0)
                __builtin_amdgcn_s_sleep(8);
        }
        __threadfence();
    }
    __syncthreads();

    // ---- phase 2: one wave per pair; 32-lane halves gather A/B concurrently ----
    float bias = bptr[0];
    for (int p = w; p < pairs; p += NWAVES) {
        int i0 = bounds[2 * p];
        int i1 = bounds[2 * p + 1];
        int i2 = bounds[2 * p + 2];

        bool hi  = (lane >= 32);
        int  beg = hi ? i1 : i0;
        int  end = hi ? i2 : i1;

        float s = 0.f;
        for (int j = beg + (lane & 31); j < end; j += 32) {
            float2 d = dot2[token_ids[j]];
            s += hi ? d.y : d.x;
        }
        #pragma unroll
        for (int m = 16; m > 0; m >>= 1) s += __shfl_xor(s, m, 64);
        float other = __shfl_xor(s, 32, 64);  // lane0 <- lane32's B-sum

        if (lane == 0) {
            float m0 = s     / fmaxf((float)(i1 - i0), 1.0f);
            float m1 = other / fmaxf((float)(i2 - i1), 1.0f);
            float logit = m0 + m1 + bias;
            out[p] = 1.0f / (1.0f + expf(-logit));
        }
    }
}

extern "C" void kernel_launch(void* const* d_in, const int* in_sizes, int n_in,
                              void* d_out, int out_size, void* d_ws, size_t ws_size,
                              hipStream_t stream) {
    const float* emb         = (const float*)d_in[0];
    const float* W           = (const float*)d_in[1];
    const float* b           = (const float*)d_in[2];
    const int*   token_ids   = (const int*)d_in[3];
    const int*   segment_ids = (const int*)d_in[4];

    const int T     = in_sizes[3];
    const int vocab = in_sizes[0] / EMB;
    const int pairs = out_size;
    const int nseg  = pairs * 2;

    Ctrl*   ctrl   = (Ctrl*)d_ws;
    float2* dot2   = (float2*)((char*)d_ws + 256);  // 100000 * 8B
    int*    bounds = (int*)(dot2 + vocab);          // (nseg+1) * 4B

    // zero barrier state each call (deterministic across graph replays)
    hipMemsetAsync(ctrl, 0, sizeof(Ctrl), stream);

    mega_kernel<<<NBLK, NTHR, 0, stream>>>(
        emb, W, token_ids, segment_ids, b,
        dot2, bounds, ctrl, (float*)d_out,
        vocab, T, nseg, pairs);
}

// Round 12
// 70.454 us; speedup vs baseline: 2.0856x; 2.0856x over previous
//
#include <hip/hip_runtime.h>

#define EMB 300
#define EMB4 75            // 300/4
#define NBLK 1024
#define NTHR 256
#define NWAVES (NBLK * NTHR / 64)   // 4096
#define NCNT 32                     // arrival counters (spread across lines)
#define CSTRIDE 64                  // ints between counters (256B apart)

// ctrl layout (ints): [0 .. NCNT*CSTRIDE) arrival counters (padded),
//                     [NCNT*CSTRIDE]       master counter,
//                     [NCNT*CSTRIDE + 64]  release flag
#define CTRL_INTS (NCNT * CSTRIDE + 128)

// One persistent kernel, static work partitioning:
//   phase 0: boundary sweep of sorted segment_ids -> bounds[]
//   phase 1: dot2[v] = (emb[v]·W[:300], emb[v]·W[300:])
//   barrier: hierarchical arrive (acq_rel) + RELAXED poll + one acquire fence
//   phase 2: per-pair gather + mean + sigmoid
__global__ __launch_bounds__(NTHR, 4)
void mega_kernel(const float* __restrict__ emb,
                 const float* __restrict__ W,
                 const int* __restrict__ token_ids,
                 const int* __restrict__ segment_ids,
                 const float* __restrict__ bptr,
                 float2* __restrict__ dot2,
                 int* __restrict__ bounds,
                 int* __restrict__ ctrl,
                 float* __restrict__ out,
                 int vocab, int T, int nseg, int pairs) {
    const int gtid = blockIdx.x * NTHR + threadIdx.x;
    const int lane = threadIdx.x & 63;
    const int w    = gtid >> 6;

    // ---- phase 0: segment boundaries (sorted ids -> transition scan) ----
    for (int j = gtid; j < T; j += NBLK * NTHR) {
        int cur = segment_ids[j];
        if (j == 0) {
            for (int s = 0; s <= cur; ++s) bounds[s] = 0;
        } else {
            int prev = segment_ids[j - 1];
            for (int s = prev + 1; s <= cur; ++s) bounds[s] = j;
        }
        if (j == T - 1) {
            for (int s = cur + 1; s <= nseg; ++s) bounds[s] = T;
        }
    }

    // ---- phase 1: dot products, 4 rows per wave-iteration, static stride ----
    const float4* W4 = (const float4*)W;   // 600 floats = 150 float4
    const int l  = lane & 15;              // lane within 16-lane group
    const int gq = lane >> 4;              // which of the wave's 4 rows

    float4 wa[5], wb[5];
    #pragma unroll
    for (int it = 0; it < 5; ++it) {
        int k = l + it * 16;
        wa[it] = (k < EMB4) ? W4[k]        : make_float4(0.f, 0.f, 0.f, 0.f);
        wb[it] = (k < EMB4) ? W4[EMB4 + k] : make_float4(0.f, 0.f, 0.f, 0.f);
    }

    const int  ngroups = vocab >> 2;          // vocab divisible by 4 here
    const bool tail_ok = (l < EMB4 - 64);     // l < 11: 5th float4 exists
    for (int rg = w; rg < ngroups; rg += NWAVES) {
        unsigned row = (unsigned)(rg * 4 + gq);
        const float4* e4 = (const float4*)(emb + row * (unsigned)EMB);

        float a = 0.f, b = 0.f;
        #pragma unroll
        for (int it = 0; it < 4; ++it) {      // k = l + 16*it <= 63 < 75
            float4 v = e4[l + it * 16];
            a += v.x * wa[it].x + v.y * wa[it].y + v.z * wa[it].z + v.w * wa[it].w;
            b += v.x * wb[it].x + v.y * wb[it].y + v.z * wb[it].z + v.w * wb[it].w;
        }
        if (tail_ok) {                        // k = l + 64 < 75
            float4 v = e4[l + 64];
            a += v.x * wa[4].x + v.y * wa[4].y + v.z * wa[4].z + v.w * wa[4].w;
            b += v.x * wb[4].x + v.y * wb[4].y + v.z * wb[4].z + v.w * wb[4].w;
        }
        #pragma unroll
        for (int m = 8; m > 0; m >>= 1) {
            a += __shfl_xor(a, m, 64);
            b += __shfl_xor(b, m, 64);
        }
        if (l == 0) dot2[row] = make_float2(a, b);
    }

    // ---- grid barrier: hierarchical arrive, relaxed poll, one acquire fence ----
    volatile int* release = ctrl + NCNT * CSTRIDE + 64;
    __syncthreads();   // all block's stores issued & counted
    if (threadIdx.x == 0) {
        int* cnt    = ctrl + (blockIdx.x & (NCNT - 1)) * CSTRIDE;
        int* master = ctrl + NCNT * CSTRIDE;
        // acq_rel RMW: releases this block's writes, acquires earlier blocks'
        int prev = __hip_atomic_fetch_add(cnt, 1, __ATOMIC_ACQ_REL,
                                          __HIP_MEMORY_SCOPE_AGENT);
        if (prev == (NBLK / NCNT) - 1) {   // last block on this counter
            int m = __hip_atomic_fetch_add(master, 1, __ATOMIC_ACQ_REL,
                                           __HIP_MEMORY_SCOPE_AGENT);
            if (m == NCNT - 1) {           // last counter -> open the gate
                __hip_atomic_store((int*)release, 1, __ATOMIC_RELEASE,
                                   __HIP_MEMORY_SCOPE_AGENT);
            }
        }
        // relaxed polls: no per-poll cache invalidation
        while (__hip_atomic_load((int*)release, __ATOMIC_RELAXED,
                                 __HIP_MEMORY_SCOPE_AGENT) == 0)
            __builtin_amdgcn_s_sleep(32);
        // one acquire fence: makes all blocks' phase-0/1 writes visible
        __builtin_amdgcn_fence(__ATOMIC_ACQUIRE, "agent");
    }
    __syncthreads();

    // ---- phase 2: one wave per pair; 32-lane halves gather A/B concurrently ----
    float bias = bptr[0];
    for (int p = w; p < pairs; p += NWAVES) {
        int i0 = bounds[2 * p];
        int i1 = bounds[2 * p + 1];
        int i2 = bounds[2 * p + 2];

        bool hi  = (lane >= 32);
        int  beg = hi ? i1 : i0;
        int  end = hi ? i2 : i1;

        float s = 0.f;
        for (int j = beg + (lane & 31); j < end; j += 32) {
            float2 d = dot2[token_ids[j]];
            s += hi ? d.y : d.x;
        }
        #pragma unroll
        for (int m = 16; m > 0; m >>= 1) s += __shfl_xor(s, m, 64);
        float other = __shfl_xor(s, 32, 64);  // lane0 <- lane32's B-sum

        if (lane == 0) {
            float m0 = s     / fmaxf((float)(i1 - i0), 1.0f);
            float m1 = other / fmaxf((float)(i2 - i1), 1.0f);
            float logit = m0 + m1 + bias;
            out[p] = 1.0f / (1.0f + expf(-logit));
        }
    }
}

extern "C" void kernel_launch(void* const* d_in, const int* in_sizes, int n_in,
                              void* d_out, int out_size, void* d_ws, size_t ws_size,
                              hipStream_t stream) {
    const float* emb         = (const float*)d_in[0];
    const float* W           = (const float*)d_in[1];
    const float* b           = (const float*)d_in[2];
    const int*   token_ids   = (const int*)d_in[3];
    const int*   segment_ids = (const int*)d_in[4];

    const int T     = in_sizes[3];
    const int vocab = in_sizes[0] / EMB;
    const int pairs = out_size;
    const int nseg  = pairs * 2;

    int*    ctrl   = (int*)d_ws;                         // CTRL_INTS ints
    float2* dot2   = (float2*)((char*)d_ws + 16384);     // 100000 * 8B
    int*    bounds = (int*)(dot2 + vocab);               // (nseg+1) * 4B

    // zero barrier/counter state each call (deterministic across replays)
    (void)hipMemsetAsync(ctrl, 0, CTRL_INTS * sizeof(int), stream);

    mega_kernel<<<NBLK, NTHR, 0, stream>>>(
        emb, W, token_ids, segment_ids, b,
        dot2, bounds, ctrl, (float*)d_out,
        vocab, T, nseg, pairs);
}

// Round 13
// 31.204 us; speedup vs baseline: 4.7090x; 2.2578x over previous
//
#include <hip/hip_runtime.h>

#define EMB 300
#define EMB4 75  // 300/4

// Fused kernel 1 (proven R6 structure):
//   blocks [0, blocks_bnd): boundary sweep over sorted segment_ids:
//       bounds[s] = first token index with segment_ids >= s, s in [0, nseg]
//   blocks [blocks_bnd, gridDim): dot2[v] = (emb[v]·W[:300], emb[v]·W[300:])
//       grid-stride over 4-row groups; 16-lane group per row; W in registers;
//       branch-free inner loop (4 unconditional float4 iters + masked tail).
__global__ void fused1_kernel(const float* __restrict__ emb,
                              const float* __restrict__ W,
                              const int* __restrict__ segment_ids,
                              float2* __restrict__ dot2,
                              int* __restrict__ bounds,
                              int vocab, int T, int nseg, int blocks_bnd) {
    if ((int)blockIdx.x < blocks_bnd) {
        // ---- boundary pass: one streaming sweep of segment_ids ----
        int tid    = blockIdx.x * blockDim.x + threadIdx.x;
        int stride = blocks_bnd * blockDim.x;
        for (int j = tid; j < T; j += stride) {
            int cur = segment_ids[j];
            if (j == 0) {
                for (int s = 0; s <= cur; ++s) bounds[s] = 0;
            } else {
                int prev = segment_ids[j - 1];
                for (int s = prev + 1; s <= cur; ++s) bounds[s] = j;
            }
            if (j == T - 1) {
                for (int s = cur + 1; s <= nseg; ++s) bounds[s] = T;
            }
        }
    } else {
        // ---- dot pass ----
        const float4* W4 = (const float4*)W;  // 600 floats = 150 float4
        int wave   = ((blockIdx.x - blocks_bnd) * blockDim.x + threadIdx.x) >> 6;
        int nwaves = ((gridDim.x - blocks_bnd) * blockDim.x) >> 6;
        int lane   = threadIdx.x & 63;
        int l      = lane & 15;   // lane within 16-lane group
        int gq     = lane >> 4;   // which of the wave's 4 rows

        float4 wa[5], wb[5];
        #pragma unroll
        for (int it = 0; it < 5; ++it) {
            int k = l + it * 16;
            wa[it] = (k < EMB4) ? W4[k]        : make_float4(0.f, 0.f, 0.f, 0.f);
            wb[it] = (k < EMB4) ? W4[EMB4 + k] : make_float4(0.f, 0.f, 0.f, 0.f);
        }

        const int  ngroups = vocab >> 2;          // vocab divisible by 4 here
        const bool tail_ok = (l < EMB4 - 64);     // l < 11: 5th float4 exists
        for (int rg = wave; rg < ngroups; rg += nwaves) {
            unsigned row = (unsigned)(rg * 4 + gq);
            const float4* e4 = (const float4*)(emb + row * (unsigned)EMB);

            float a = 0.f, b = 0.f;
            #pragma unroll
            for (int it = 0; it < 4; ++it) {      // k = l + 16*it <= 63 < 75
                float4 v = e4[l + it * 16];
                a += v.x * wa[it].x + v.y * wa[it].y +
                     v.z * wa[it].z + v.w * wa[it].w;
                b += v.x * wb[it].x + v.y * wb[it].y +
                     v.z * wb[it].z + v.w * wb[it].w;
            }
            if (tail_ok) {                        // k = l + 64 < 75
                float4 v = e4[l + 64];
                a += v.x * wa[4].x + v.y * wa[4].y +
                     v.z * wa[4].z + v.w * wa[4].w;
                b += v.x * wb[4].x + v.y * wb[4].y +
                     v.z * wb[4].z + v.w * wb[4].w;
            }
            #pragma unroll
            for (int m = 8; m > 0; m >>= 1) {
                a += __shfl_xor(a, m, 64);
                b += __shfl_xor(b, m, 64);
            }
            if (l == 0) dot2[row] = make_float2(a, b);
        }
    }
}

// Kernel 2: one wave per output pair; lanes 0-31 gather segment A,
// lanes 32-63 gather segment B concurrently; single xor-reduce tree.
__global__ void pair_kernel(const int* __restrict__ token_ids,
                            const int* __restrict__ bounds,
                            const float2* __restrict__ dot2,
                            const float* __restrict__ bptr,
                            float* __restrict__ out,
                            int pairs) {
    int wave = (blockIdx.x * blockDim.x + threadIdx.x) >> 6;
    int lane = threadIdx.x & 63;
    if (wave >= pairs) return;

    int i0 = bounds[2 * wave];
    int i1 = bounds[2 * wave + 1];
    int i2 = bounds[2 * wave + 2];

    bool hi  = (lane >= 32);
    int  beg = hi ? i1 : i0;
    int  end = hi ? i2 : i1;

    float s = 0.f;
    for (int j = beg + (lane & 31); j < end; j += 32) {
        float2 d = dot2[token_ids[j]];
        s += hi ? d.y : d.x;
    }
    #pragma unroll
    for (int m = 16; m > 0; m >>= 1) s += __shfl_xor(s, m, 64);
    float other = __shfl_xor(s, 32, 64);  // lane0 <- lane32's B-sum

    if (lane == 0) {
        float m0 = s     / fmaxf((float)(i1 - i0), 1.0f);
        float m1 = other / fmaxf((float)(i2 - i1), 1.0f);
        float logit = m0 + m1 + bptr[0];
        out[wave] = 1.0f / (1.0f + expf(-logit));
    }
}

extern "C" void kernel_launch(void* const* d_in, const int* in_sizes, int n_in,
                              void* d_out, int out_size, void* d_ws, size_t ws_size,
                              hipStream_t stream) {
    const float* emb         = (const float*)d_in[0];
    const float* W           = (const float*)d_in[1];
    const float* b           = (const float*)d_in[2];
    const int*   token_ids   = (const int*)d_in[3];
    const int*   segment_ids = (const int*)d_in[4];

    const int T     = in_sizes[3];
    const int vocab = in_sizes[0] / EMB;
    const int pairs = out_size;
    const int nseg  = pairs * 2;

    float2* dot2   = (float2*)d_ws;          // 100000 * 8B = 800 KB
    int*    bounds = (int*)(dot2 + vocab);   // (nseg+1) * 4B

    // bounds blocks first so pair inputs are ready earliest; 1024 dot blocks
    // (R6's best: 16 waves/CU; R9 showed 2048 gains nothing).
    int blocks_bnd = 256;
    int blocks_dot = 1024;
    fused1_kernel<<<blocks_bnd + blocks_dot, 256, 0, stream>>>(
        emb, W, segment_ids, dot2, bounds, vocab, T, nseg, blocks_bnd);

    // one wave per pair, 4 waves per block.
    pair_kernel<<<(pairs + 3) / 4, 256, 0, stream>>>(
        token_ids, bounds, dot2, b, (float*)d_out, pairs);
}